// Round 16
// baseline (375.589 us; speedup 1.0000x reference)
//
#include <hip/hip_runtime.h>
#include <hip/hip_bf16.h>

// ---------------- helpers ----------------
typedef __attribute__((ext_vector_type(8))) short bf16x8;
typedef __attribute__((ext_vector_type(4))) float f32x4;
typedef __attribute__((ext_vector_type(2))) float f32x2;

__device__ __forceinline__ unsigned short f2bf(float f) {
    __hip_bfloat16 h = __float2bfloat16(f);   // round-to-nearest-even
    return __builtin_bit_cast(unsigned short, h);
}
__device__ __forceinline__ unsigned int packbf(float lo, float hi) {
    return (unsigned int)f2bf(lo) | ((unsigned int)f2bf(hi) << 16);
}

// ---------------- CSR build ----------------
__global__ void k_hist(const int* __restrict__ dst, int* __restrict__ counts,
                       int* __restrict__ rank, int E) {
    int e = blockIdx.x * blockDim.x + threadIdx.x;
    if (e < E) rank[e] = atomicAdd(&counts[dst[e]], 1);
}

__global__ void k_psum(const int* __restrict__ counts, int* __restrict__ part, int NN) {
    __shared__ int s[256];
    int t = threadIdx.x;
    int i = blockIdx.x * 256 + t;
    s[t] = (i < NN) ? counts[i] : 0;
    __syncthreads();
    for (int off = 128; off > 0; off >>= 1) {
        if (t < off) s[t] += s[t + off];
        __syncthreads();
    }
    if (t == 0) part[blockIdx.x] = s[0];
}

__global__ void k_scatter_rs(const int* __restrict__ counts, const int* __restrict__ part,
                             int* __restrict__ row_start, int NN, int E) {
    __shared__ int s[256];
    __shared__ int q[256];
    int t = threadIdx.x;
    int b = blockIdx.x;
    q[t] = (t < b) ? part[t] : 0;
    __syncthreads();
    for (int off = 128; off > 0; off >>= 1) {
        if (t < off) q[t] += q[t + off];
        __syncthreads();
    }
    int boff = q[0];
    __syncthreads();
    int i = b * 256 + t;
    int v = (i < NN) ? counts[i] : 0;
    s[t] = v; __syncthreads();
    for (int off = 1; off < 256; off <<= 1) {
        int u = (t >= off) ? s[t - off] : 0;
        __syncthreads();
        s[t] += u;
        __syncthreads();
    }
    int ex = s[t] - v + boff;
    if (i < NN) row_start[i] = ex;
    if (i == NN - 1) row_start[NN] = E;
}

__global__ void k_fill(const int* __restrict__ src, const int* __restrict__ dst,
                       const int* __restrict__ rank, const int* __restrict__ row_start,
                       unsigned short* __restrict__ csrc, int E) {
    int e = blockIdx.x * blockDim.x + threadIdx.x;
    if (e < E) csrc[row_start[dst[e]] + rank[e]] = (unsigned short)src[e];
}

// ---------------- fused dtype conversions (one launch) ----------------
// x is quantized to SIGNED int8 with a per-node fp32 scale (one wave per
// node: 2 f32/lane, 6-shfl absmax, packed ushort store -> 128-B rows).
__global__ void k_cvt_all(const float* __restrict__ x, unsigned char* __restrict__ xq,
                          float* __restrict__ xsc, int M, int nbq,
                          const float* __restrict__ W1, unsigned short* __restrict__ w1t,
                          const float* __restrict__ W2, unsigned short* __restrict__ w2t,
                          const float* __restrict__ W3, unsigned short* __restrict__ w3t) {
    int b = blockIdx.x;
    int tid = threadIdx.x;
    if (b < nbq) {
        int node = b * 4 + (tid >> 6);
        if (node < M) {
            int lane = tid & 63;
            float2 v = ((const float2*)x)[(size_t)node * 64 + lane];
            float m = fmaxf(fabsf(v.x), fabsf(v.y));
#pragma unroll
            for (int off = 1; off <= 32; off <<= 1)
                m = fmaxf(m, __shfl_xor(m, off, 64));
            float inv = m > 0.f ? 127.0f / m : 0.f;
            int qx = (int)rintf(v.x * inv);
            int qy = (int)rintf(v.y * inv);
            unsigned pk = (unsigned)(qx & 0xff) | ((unsigned)(qy & 0xff) << 8);
            ((unsigned short*)xq)[(size_t)node * 64 + lane] = (unsigned short)pk;
            if (lane == 0) xsc[node] = m * (1.0f / 127.0f);
        }
        return;
    }
    b -= nbq;
    const float* w; unsigned short* wt; int K;
    if (b < 128)      { w = W1; wt = w1t; K = 128; }
    else if (b < 384) { w = W2; wt = w2t; K = 256; b -= 128; }
    else              { w = W3; wt = w3t; K = 256; b -= 384; }
    int i = b * 256 + tid;           // i < K*256
    int k = i >> 8, n = i & 255;
    wt[n * K + k] = f2bf(w[i]);
}

// ---------------- FUSED agg + MFMA GEMM per layer ----------------
// Seven agg-loop variants plateaued at ~42 us (VALU-issue ~26us + 205 MB
// register delivery / 89 MB L2-miss service ~35-40us) -> agg is at its
// floor under the split structure. This kernel fuses agg+GEMM:
//   block = 64 nodes x 4 waves.
//   Phase 1: wave wv gathers node rows wv*16..+15 (round-6 best inner
//     loop: full-wave-per-edge, ping-pong-2, zero-row demask) and packs
//     bf16 rows into LDS A[64][K+8] (pad 8 -> 2-way bank alias = free).
//   Phase 2 (one barrier): MFMA, A from LDS, B-frags from L2-resident
//     Wt, epilogue = quant8(h8+scales) or fp32.
// Wins: ab intermediate gone (25 MB write + ~100 MB read per layer),
// GEMM hides under other blocks' gather stalls, 3 fewer launches.
// tbl has M+1 rows; row M has scale 0 (zero-row demask).
template <bool QUANT, int K>
__global__ __launch_bounds__(256, 4)
void k_fused(const unsigned char* __restrict__ tbl, const float* __restrict__ tsc,
             const int* __restrict__ rs, const unsigned short* __restrict__ csrc,
             const unsigned short* __restrict__ Bt, const float* __restrict__ bias,
             void* __restrict__ Cout, float* __restrict__ oscales, int M) {
    constexpr int LDA = K + 8;
    __shared__ unsigned short As[64 * LDA];
    int tid = threadIdx.x;
    int lane = tid & 63, wv = tid >> 6;
    int node0 = blockIdx.x * 64;

    // ---- phase 1: gather 16 node rows per wave into As ----
    {
        const unsigned char* hl = tbl + lane * (K == 256 ? 4 : 2);
        int q = lane >> 4;
        for (int i = 0; i < 16; ++i) {
            int nloc = wv * 16 + i;
            int node = node0 + nloc;
            f32x2 a0 = {0.f, 0.f}, a1 = {0.f, 0.f};
            if (node < M) {
                int k0 = rs[node];
                int cnt = rs[node + 1] - k0;
                for (int base = 0; base < cnt; base += 64) {
                    int nk = min(cnt - base, 64);
                    int myidx = (lane < nk) ? (int)csrc[k0 + base + lane] : M;  // M = zero row
                    int nb = (nk + 3) >> 2;

                    unsigned vA[4], vB[4]; float sA[4], sB[4];
                    auto issue = [&](int j, unsigned (&v)[4], float (&s)[4]) {
#pragma unroll
                        for (int b = 0; b < 4; ++b) {
                            int row = __shfl(myidx, j + b, 64);
                            if constexpr (K == 256) {
                                v[b] = *(const unsigned*)(hl + ((size_t)row << 8));
                                s[b] = tsc[(row << 2) + q];
                            } else {
                                v[b] = *(const unsigned short*)(hl + ((size_t)row << 7));
                                s[b] = tsc[row];
                            }
                        }
                    };
                    auto consume = [&](unsigned (&v)[4], float (&s)[4]) {
#pragma unroll
                        for (int b = 0; b < 4; ++b) {
                            f32x2 s2 = {s[b], s[b]};
                            unsigned x = v[b];
                            if constexpr (K == 256) {
                                a0 += (f32x2){(float)(x & 0xff), (float)((x >> 8) & 0xff)} * s2;
                                a1 += (f32x2){(float)((x >> 16) & 0xff), (float)(x >> 24)} * s2;
                            } else {
                                int b0 = (int)(signed char)(x & 0xff);
                                int b1 = (int)(signed char)((x >> 8) & 0xff);
                                a0 += (f32x2){(float)b0, (float)b1} * s2;
                            }
                        }
                    };

                    issue(0, vA, sA);
                    for (int b = 1; b < nb; ++b) {
                        if (b & 1) { issue(b * 4, vB, sB); consume(vA, sA); }
                        else       { issue(b * 4, vA, sA); consume(vB, sB); }
                    }
                    if (nb & 1) consume(vA, sA);
                    else        consume(vB, sB);
                }
            }
            // pack bf16 row into LDS (zeros for tail nodes keep MFMA defined)
            if constexpr (K == 256) {
                uint2 o; o.x = packbf(a0.x, a0.y); o.y = packbf(a1.x, a1.y);
                *(uint2*)&As[nloc * LDA + lane * 4] = o;
            } else {
                *(unsigned*)&As[nloc * LDA + lane * 2] = packbf(a0.x, a0.y);
            }
        }
    }
    __syncthreads();

    // ---- phase 2: C[64 x 256] = relu(As @ Bt^T + bias); wave wv owns cols wv*64.. ----
    int quad = lane >> 4, l16 = lane & 15;
    int cb = wv * 64;
    f32x4 acc[4][4];
#pragma unroll
    for (int i = 0; i < 4; ++i)
#pragma unroll
        for (int j = 0; j < 4; ++j) acc[i][j] = (f32x4){0.f, 0.f, 0.f, 0.f};

#pragma unroll
    for (int s = 0; s < K / 32; ++s) {
        bf16x8 af[4], bfr[4];
#pragma unroll
        for (int mt = 0; mt < 4; ++mt)
            af[mt] = *((const bf16x8*)&As[(mt * 16 + l16) * LDA + s * 32 + quad * 8]);
#pragma unroll
        for (int nt = 0; nt < 4; ++nt)
            bfr[nt] = *((const bf16x8*)(Bt + (size_t)(cb + nt * 16 + l16) * K + s * 32 + quad * 8));
#pragma unroll
        for (int mt = 0; mt < 4; ++mt)
#pragma unroll
            for (int nt = 0; nt < 4; ++nt)
                acc[mt][nt] = __builtin_amdgcn_mfma_f32_16x16x32_bf16(af[mt], bfr[nt], acc[mt][nt], 0, 0, 0);
    }

    // bias + relu.  C/D layout: col = lane&15, row = quad*4 + reg
    float bv[4];
#pragma unroll
    for (int nt = 0; nt < 4; ++nt) bv[nt] = bias[cb + nt * 16 + l16];
#pragma unroll
    for (int mt = 0; mt < 4; ++mt)
#pragma unroll
        for (int nt = 0; nt < 4; ++nt)
#pragma unroll
            for (int r = 0; r < 4; ++r) {
                float v = acc[mt][nt][r] + bv[nt];
                acc[mt][nt][r] = v > 0.f ? v : 0.f;
            }

    if constexpr (QUANT) {
        unsigned char* h8 = (unsigned char*)Cout;
        int qid = wv;                    // 64-col quarter id
#pragma unroll
        for (int mt = 0; mt < 4; ++mt) {
#pragma unroll
            for (int r = 0; r < 4; ++r) {
                float mx = fmaxf(fmaxf(acc[mt][0][r], acc[mt][1][r]),
                                 fmaxf(acc[mt][2][r], acc[mt][3][r]));
#pragma unroll
                for (int off = 1; off < 16; off <<= 1)
                    mx = fmaxf(mx, __shfl_xor(mx, off, 64));
                float inv = mx > 0.f ? 255.0f / mx : 0.0f;
                int m = node0 + mt * 16 + quad * 4 + r;
                if (m < M) {
#pragma unroll
                    for (int nt = 0; nt < 4; ++nt) {
                        int n = cb + nt * 16 + l16;
                        unsigned u = (unsigned)(acc[mt][nt][r] * inv + 0.5f);
                        h8[(size_t)m * 256 + n] = (unsigned char)u;
                    }
                    if (l16 == 0) oscales[(size_t)m * 4 + qid] = mx * (1.0f / 255.0f);
                }
            }
        }
    } else {
        float* C = (float*)Cout;
#pragma unroll
        for (int mt = 0; mt < 4; ++mt)
#pragma unroll
            for (int nt = 0; nt < 4; ++nt) {
                int n = cb + nt * 16 + l16;
#pragma unroll
                for (int r = 0; r < 4; ++r) {
                    int m = node0 + mt * 16 + quad * 4 + r;
                    if (m < M) C[(size_t)m * 256 + n] = acc[mt][nt][r];
                }
            }
    }
}

// ---------------- host ----------------
static inline size_t alignup(size_t x) { return (x + 255) & ~(size_t)255; }

extern "C" void kernel_launch(void* const* d_in, const int* in_sizes, int n_in,
                              void* d_out, int out_size, void* d_ws, size_t ws_size,
                              hipStream_t stream) {
    const float* x  = (const float*)d_in[0];
    const int* ei   = (const int*)d_in[1];    // int32 on device (harness converts)
    const float* W1 = (const float*)d_in[2];
    const float* b1 = (const float*)d_in[3];
    const float* W2 = (const float*)d_in[4];
    const float* b2 = (const float*)d_in[5];
    const float* W3 = (const float*)d_in[6];
    const float* b3 = (const float*)d_in[7];

    const int M = in_sizes[0] / 128;      // 50000 nodes
    const int E = in_sizes[1] / 2;        // 800000 edges
    const int* srcp = ei;
    const int* dstp = ei + E;
    const int nscan = (M + 255) / 256;

    // workspace carve-up (~38 MB). h8a/h8b double-buffer the int8 hidden
    // activations so a fused kernel never reads and writes the same table.
    // d_out holds only the final fp32 output.
    char* p = (char*)d_ws;
    size_t off = 0;
    auto carve = [&](size_t bytes) { void* r = p + off; off += alignup(bytes); return r; };
    int* counts    = (int*)carve((size_t)M * 4);
    int* row_start = (int*)carve((size_t)(M + 1) * 4);
    int* part      = (int*)carve((size_t)256 * 4);
    int* rank      = (int*)carve((size_t)E * 4);
    unsigned short* csrc = (unsigned short*)carve((size_t)E * 2);
    unsigned short* w1t = (unsigned short*)carve((size_t)128 * 256 * 2);
    unsigned short* w2t = (unsigned short*)carve((size_t)256 * 256 * 2);
    unsigned short* w3t = (unsigned short*)carve((size_t)256 * 256 * 2);
    unsigned char* xq   = (unsigned char*)carve((size_t)(M + 1) * 128);   // int8 x (+zero row)
    float* xsc          = (float*)carve((size_t)(M + 1) * 4);
    unsigned char* h8a  = (unsigned char*)carve((size_t)(M + 1) * 256);   // h1 int8 (+zero row)
    float* sca          = (float*)carve((size_t)(M + 1) * 16);
    unsigned char* h8b  = (unsigned char*)carve((size_t)(M + 1) * 256);   // h2 int8 (+zero row)
    float* scb          = (float*)carve((size_t)(M + 1) * 16);

    // 1) CSR build (rank trick: no atomics in fill); zero-row scales
    hipMemsetAsync(counts, 0, (size_t)M * 4, stream);
    hipMemsetAsync(xsc + M, 0, 4, stream);
    hipMemsetAsync(sca + (size_t)M * 4, 0, 16, stream);
    hipMemsetAsync(scb + (size_t)M * 4, 0, 16, stream);
    k_hist<<<(E + 255) / 256, 256, 0, stream>>>(dstp, counts, rank, E);
    k_psum<<<nscan, 256, 0, stream>>>(counts, part, M);
    k_scatter_rs<<<nscan, 256, 0, stream>>>(counts, part, row_start, M, E);
    k_fill<<<(E + 255) / 256, 256, 0, stream>>>(srcp, dstp, rank, row_start, csrc, E);

    // 2) conversions (single launch): x -> int8 + per-node scale, W -> bf16^T
    int nbq = (M + 3) / 4;
    k_cvt_all<<<nbq + 128 + 256 + 256, 256, 0, stream>>>(
        x, xq, xsc, M, nbq, W1, w1t, W2, w2t, W3, w3t);

    int fblocks = (M + 63) / 64;

    // layer 1: h1 = quant8(relu(agg(xq*xsc) @ W1 + b1))
    k_fused<true, 128><<<fblocks, 256, 0, stream>>>(xq, xsc, row_start, csrc, w1t, b1, h8a, sca, M);
    // layer 2: h2 = quant8(relu(agg8(h1) @ W2 + b2))
    k_fused<true, 256><<<fblocks, 256, 0, stream>>>(h8a, sca, row_start, csrc, w2t, b2, h8b, scb, M);
    // layer 3: out = relu(agg8(h2) @ W3 + b3)
    k_fused<false, 256><<<fblocks, 256, 0, stream>>>(h8b, scb, row_start, csrc, w3t, b3, d_out, nullptr, M);
}

// Round 17
// 337.687 us; speedup vs baseline: 1.1122x; 1.1122x over previous
//
#include <hip/hip_runtime.h>
#include <hip/hip_bf16.h>

// ---------------- helpers ----------------
typedef __attribute__((ext_vector_type(8))) short bf16x8;
typedef __attribute__((ext_vector_type(4))) float f32x4;
typedef __attribute__((ext_vector_type(2))) float f32x2;

__device__ __forceinline__ unsigned short f2bf(float f) {
    __hip_bfloat16 h = __float2bfloat16(f);   // round-to-nearest-even
    return __builtin_bit_cast(unsigned short, h);
}
// unpack packed bf16 pair -> f32x2 {lo, hi}
__device__ __forceinline__ f32x2 up2(unsigned int u) {
    f32x2 r;
    r.x = __builtin_bit_cast(float, u << 16);
    r.y = __builtin_bit_cast(float, u & 0xffff0000u);
    return r;
}
__device__ __forceinline__ unsigned int packbf(float lo, float hi) {
    return (unsigned int)f2bf(lo) | ((unsigned int)f2bf(hi) << 16);
}

// ---------------- CSR build ----------------
__global__ void k_hist(const int* __restrict__ dst, int* __restrict__ counts,
                       int* __restrict__ rank, int E) {
    int e = blockIdx.x * blockDim.x + threadIdx.x;
    if (e < E) rank[e] = atomicAdd(&counts[dst[e]], 1);
}

__global__ void k_psum(const int* __restrict__ counts, int* __restrict__ part, int NN) {
    __shared__ int s[256];
    int t = threadIdx.x;
    int i = blockIdx.x * 256 + t;
    s[t] = (i < NN) ? counts[i] : 0;
    __syncthreads();
    for (int off = 128; off > 0; off >>= 1) {
        if (t < off) s[t] += s[t + off];
        __syncthreads();
    }
    if (t == 0) part[blockIdx.x] = s[0];
}

__global__ void k_scatter_rs(const int* __restrict__ counts, const int* __restrict__ part,
                             int* __restrict__ row_start, int NN, int E) {
    __shared__ int s[256];
    __shared__ int q[256];
    int t = threadIdx.x;
    int b = blockIdx.x;
    q[t] = (t < b) ? part[t] : 0;
    __syncthreads();
    for (int off = 128; off > 0; off >>= 1) {
        if (t < off) q[t] += q[t + off];
        __syncthreads();
    }
    int boff = q[0];
    __syncthreads();
    int i = b * 256 + t;
    int v = (i < NN) ? counts[i] : 0;
    s[t] = v; __syncthreads();
    for (int off = 1; off < 256; off <<= 1) {
        int u = (t >= off) ? s[t - off] : 0;
        __syncthreads();
        s[t] += u;
        __syncthreads();
    }
    int ex = s[t] - v + boff;
    if (i < NN) row_start[i] = ex;
    if (i == NN - 1) row_start[NN] = E;
}

__global__ void k_fill(const int* __restrict__ src, const int* __restrict__ dst,
                       const int* __restrict__ rank, const int* __restrict__ row_start,
                       unsigned short* __restrict__ csrc, int E) {
    int e = blockIdx.x * blockDim.x + threadIdx.x;
    if (e < E) csrc[row_start[dst[e]] + rank[e]] = (unsigned short)src[e];
}

// ---------------- fused dtype conversions (one launch) ----------------
__global__ void k_cvt_all(const float4* __restrict__ x4, ushort4* __restrict__ xb4, int n4x, int nbx,
                          const float* __restrict__ W1, unsigned short* __restrict__ w1t,
                          const float* __restrict__ W2, unsigned short* __restrict__ w2t,
                          const float* __restrict__ W3, unsigned short* __restrict__ w3t) {
    int b = blockIdx.x;
    if (b < nbx) {
        int i = b * 256 + threadIdx.x;
        if (i < n4x) {
            float4 v = x4[i];
            ushort4 o; o.x = f2bf(v.x); o.y = f2bf(v.y); o.z = f2bf(v.z); o.w = f2bf(v.w);
            xb4[i] = o;
        }
        return;
    }
    b -= nbx;
    const float* w; unsigned short* wt; int K;
    if (b < 128)      { w = W1; wt = w1t; K = 128; }
    else if (b < 384) { w = W2; wt = w2t; K = 256; b -= 128; }
    else              { w = W3; wt = w3t; K = 256; b -= 384; }
    int i = b * 256 + threadIdx.x;   // i < K*256
    int k = i >> 8, n = i & 255;
    wt[n * K + k] = f2bf(w[i]);
}

// ---------------- bf16 CSR aggregation (layer 1, x table, F=128) ----------------
// MEASURED CHAMPION (round 6, 336.5 us total). Structural tree fully
// explored: ring-3 (+3.5us), 2-waves/node (+8us), XCD-shard (+50us),
// agg+GEMM fusion (+40us/layer: occupancy-starved gather) all regressed.
// Full-wave-per-edge: lane l owns bytes [4l,4l+4) of the row; per edge
// ONE 4-B load/lane, ~4 VALU, lane-private accumulators for fixed cols
// -> no cross-lane reduction, coalesced output. Ping-pong-2 keeps 8
// edges in flight.
__global__ __launch_bounds__(256)
void k_agg(const unsigned short* __restrict__ h, const int* __restrict__ rs,
           const unsigned short* __restrict__ csrc, unsigned short* __restrict__ out, int NN) {
    int gid = blockIdx.x * blockDim.x + threadIdx.x;
    int node = gid >> 6;
    if (node >= NN) return;
    int lane = threadIdx.x & 63;
    int k0 = rs[node], k1 = rs[node + 1];
    int cnt = k1 - k0;
    const unsigned char* hb = (const unsigned char*)h;

    f32x2 acc = {0.f, 0.f};

    for (int base = 0; base < cnt; base += 64) {
        int nk = min(cnt - base, 64);
        int myidx = (lane < nk) ? (int)csrc[k0 + base + lane] : 0;
        int nb = (nk + 3) >> 2;

        auto issue = [&](int j, unsigned (&v)[4]) {
#pragma unroll
            for (int b = 0; b < 4; ++b) {
                int row = __shfl(myidx, j + b, 64);
                v[b] = *(const unsigned*)(hb + (size_t)row * 256 + lane * 4);
            }
        };
        auto consume = [&](int j, unsigned (&v)[4]) {
#pragma unroll
            for (int b = 0; b < 4; ++b) {
                unsigned x = (j + b < nk) ? v[b] : 0u;
                acc += up2(x);
            }
        };

        unsigned vA[4], vB[4];
        issue(0, vA);
        for (int b = 1; b < nb; ++b) {
            if (b & 1) { issue(b * 4, vB); consume((b - 1) * 4, vA); }
            else       { issue(b * 4, vA); consume((b - 1) * 4, vB); }
        }
        if (nb & 1) consume((nb - 1) * 4, vA);
        else        consume((nb - 1) * 4, vB);
    }

    // lane owns feats {2*lane, 2*lane+1} -> coalesced 4-B store per lane
    *(unsigned*)((unsigned char*)out + (size_t)node * 256 + lane * 4) = packbf(acc.x, acc.y);
}

// ---------------- int8 CSR aggregation (layers 2&3) ----------------
// Full-wave-per-edge: lane l owns bytes [4l,4l+4) (feats 4l..4l+3) of the
// 256-B row, quarter q = lane>>4 selects the per-(row,64-col) scale.
// Per edge: 1 payload load + 1 broadcast scale load + 1 shfl + ~7 VALU.
// Masked edge slots (uniform per wave) contribute 0 via zeroed scale;
// their gather address is a real row (myidx pads with 0) -> always legal.
__global__ __launch_bounds__(256)
void k_agg8(const unsigned char* __restrict__ h8, const float* __restrict__ scales,
            const int* __restrict__ rs, const unsigned short* __restrict__ csrc,
            unsigned short* __restrict__ out, int NN) {
    int gid = blockIdx.x * blockDim.x + threadIdx.x;
    int node = gid >> 6;
    if (node >= NN) return;
    int lane = threadIdx.x & 63;
    int q = lane >> 4;                 // 64-col quarter of this lane's 4 feats
    int k0 = rs[node], k1 = rs[node + 1];
    int cnt = k1 - k0;

    f32x2 a0 = {0.f, 0.f}, a1 = {0.f, 0.f};

    for (int base = 0; base < cnt; base += 64) {
        int nk = min(cnt - base, 64);
        int myidx = (lane < nk) ? (int)csrc[k0 + base + lane] : 0;
        int nb = (nk + 3) >> 2;

        auto issue = [&](int j, unsigned (&v)[4], float (&s)[4]) {
#pragma unroll
            for (int b = 0; b < 4; ++b) {
                int row = __shfl(myidx, j + b, 64);
                v[b] = *(const unsigned*)(h8 + (size_t)row * 256 + lane * 4);
                s[b] = scales[row * 4 + q];
            }
        };
        auto consume = [&](int j, unsigned (&v)[4], float (&s)[4]) {
#pragma unroll
            for (int b = 0; b < 4; ++b) {
                float sc = (j + b < nk) ? s[b] : 0.f;
                f32x2 s2 = {sc, sc};
                unsigned x = v[b];
                a0 += (f32x2){(float)(x & 0xff), (float)((x >> 8) & 0xff)} * s2;
                a1 += (f32x2){(float)((x >> 16) & 0xff), (float)(x >> 24)} * s2;
            }
        };

        unsigned vA[4], vB[4]; float sA[4], sB[4];
        issue(0, vA, sA);
        for (int b = 1; b < nb; ++b) {
            if (b & 1) { issue(b * 4, vB, sB); consume((b - 1) * 4, vA, sA); }
            else       { issue(b * 4, vA, sA); consume((b - 1) * 4, vB, sB); }
        }
        if (nb & 1) consume((nb - 1) * 4, vA, sA);
        else        consume((nb - 1) * 4, vB, sB);
    }

    // lane owns feats [4*lane, 4*lane+4) -> coalesced 8-B store per lane
    uint2 o; o.x = packbf(a0.x, a0.y); o.y = packbf(a1.x, a1.y);
    *(uint2*)((unsigned char*)out + (size_t)node * 512 + lane * 8) = o;
}

// ---------------- MFMA GEMM: C = relu(A @ W + b) ----------------
// Stage-B-once design (round 2/4). K <= 256 so a block's 64-col B-slab
// (16-32 KB) is staged in LDS ONCE, one __syncthreads, then a fully-
// unrolled barrier-free K-loop with A direct from global (line-perfect:
// 16 rows x 64 B per fragment load) and B from LDS (padded stride K+8).
// QUANT epilogue: row-major h8 + per-(row, 64-col) fp32 scale.
template <bool QUANT, int K>
__global__ __launch_bounds__(256, 4)
void k_gemm(const unsigned short* __restrict__ A, const unsigned short* __restrict__ Bt,
            const float* __restrict__ bias, void* __restrict__ Cout,
            float* __restrict__ scales, int M) {
    constexpr int LDB = K + 8;
    __shared__ unsigned short Bs[64 * LDB];
    int tid = threadIdx.x;
    int lane = tid & 63, quad = lane >> 4, l16 = lane & 15;
    int w = tid >> 6;
    int cbase = blockIdx.x * 64;
    int mrow0 = blockIdx.y * 256 + w * 64;

    // stage the block's B slab (64 cols x K) once
    constexpr int CH = K / 8;            // uint4 chunks per slab row
    constexpr int NCH = 64 * CH;
#pragma unroll
    for (int ch = tid; ch < NCH; ch += 256) {
        int c = ch / CH;
        int kk = (ch % CH) * 8;
        uint4 v = *((const uint4*)(Bt + (size_t)(cbase + c) * K + kk));
        *((uint4*)&Bs[c * LDB + kk]) = v;
    }
    __syncthreads();

    // A fragment base pointers (rows clamped; tail rows never stored)
    const unsigned short* Ap[4];
#pragma unroll
    for (int mt = 0; mt < 4; ++mt) {
        int r = mrow0 + mt * 16 + l16;
        if (r >= M) r = M - 1;
        Ap[mt] = A + (size_t)r * K + quad * 8;
    }

    f32x4 acc[4][4];
#pragma unroll
    for (int i = 0; i < 4; ++i)
#pragma unroll
        for (int j = 0; j < 4; ++j) acc[i][j] = (f32x4){0.f, 0.f, 0.f, 0.f};

#pragma unroll
    for (int s = 0; s < K / 32; ++s) {
        bf16x8 af[4], bfr[4];
#pragma unroll
        for (int mt = 0; mt < 4; ++mt) af[mt] = *((const bf16x8*)(Ap[mt] + s * 32));
#pragma unroll
        for (int nt = 0; nt < 4; ++nt)
            bfr[nt] = *((const bf16x8*)&Bs[(nt * 16 + l16) * LDB + s * 32 + quad * 8]);
#pragma unroll
        for (int mt = 0; mt < 4; ++mt)
#pragma unroll
            for (int nt = 0; nt < 4; ++nt)
                acc[mt][nt] = __builtin_amdgcn_mfma_f32_16x16x32_bf16(af[mt], bfr[nt], acc[mt][nt], 0, 0, 0);
    }

    // bias + relu in-place.  C/D layout: col = lane&15, row = quad*4 + reg
    float bv[4];
#pragma unroll
    for (int nt = 0; nt < 4; ++nt) bv[nt] = bias[cbase + nt * 16 + l16];
#pragma unroll
    for (int mt = 0; mt < 4; ++mt)
#pragma unroll
        for (int nt = 0; nt < 4; ++nt)
#pragma unroll
            for (int r = 0; r < 4; ++r) {
                float v = acc[mt][nt][r] + bv[nt];
                acc[mt][nt][r] = v > 0.f ? v : 0.f;
            }

    if constexpr (QUANT) {
        unsigned char* h8 = (unsigned char*)Cout;
        int qid = blockIdx.x;            // 64-col quarter id
#pragma unroll
        for (int mt = 0; mt < 4; ++mt) {
#pragma unroll
            for (int r = 0; r < 4; ++r) {
                float mx = fmaxf(fmaxf(acc[mt][0][r], acc[mt][1][r]),
                                 fmaxf(acc[mt][2][r], acc[mt][3][r]));
#pragma unroll
                for (int off = 1; off < 16; off <<= 1)
                    mx = fmaxf(mx, __shfl_xor(mx, off, 64));
                float inv = mx > 0.f ? 255.0f / mx : 0.0f;
                int m = mrow0 + mt * 16 + quad * 4 + r;
                if (m < M) {
#pragma unroll
                    for (int nt = 0; nt < 4; ++nt) {
                        int n = cbase + nt * 16 + l16;
                        unsigned u = (unsigned)(acc[mt][nt][r] * inv + 0.5f);
                        h8[(size_t)m * 256 + n] = (unsigned char)u;
                    }
                    if (l16 == 0) scales[(size_t)m * 4 + qid] = mx * (1.0f / 255.0f);
                }
            }
        }
    } else {
        float* C = (float*)Cout;
#pragma unroll
        for (int mt = 0; mt < 4; ++mt)
#pragma unroll
            for (int nt = 0; nt < 4; ++nt) {
                int n = cbase + nt * 16 + l16;
#pragma unroll
                for (int r = 0; r < 4; ++r) {
                    int m = mrow0 + mt * 16 + quad * 4 + r;
                    if (m < M) C[(size_t)m * 256 + n] = acc[mt][nt][r];
                }
            }
    }
}

// ---------------- host ----------------
static inline size_t alignup(size_t x) { return (x + 255) & ~(size_t)255; }

extern "C" void kernel_launch(void* const* d_in, const int* in_sizes, int n_in,
                              void* d_out, int out_size, void* d_ws, size_t ws_size,
                              hipStream_t stream) {
    const float* x  = (const float*)d_in[0];
    const int* ei   = (const int*)d_in[1];    // int32 on device (harness converts)
    const float* W1 = (const float*)d_in[2];
    const float* b1 = (const float*)d_in[3];
    const float* W2 = (const float*)d_in[4];
    const float* b2 = (const float*)d_in[5];
    const float* W3 = (const float*)d_in[6];
    const float* b3 = (const float*)d_in[7];

    const int M = in_sizes[0] / 128;      // 50000 nodes
    const int E = in_sizes[1] / 2;        // 800000 edges
    const int* srcp = ei;
    const int* dstp = ei + E;
    const int nscan = (M + 255) / 256;

    // workspace carve-up. h8 (12.8 MB) + scales (0.8 MB) live in d_out:
    // both dead before gemm3 overwrites d_out with fp32.
    char* p = (char*)d_ws;
    size_t off = 0;
    auto carve = [&](size_t bytes) { void* r = p + off; off += alignup(bytes); return r; };
    int* counts    = (int*)carve((size_t)M * 4);
    int* row_start = (int*)carve((size_t)(M + 1) * 4);
    int* part      = (int*)carve((size_t)256 * 4);
    int* rank      = (int*)carve((size_t)E * 4);
    unsigned short* csrc = (unsigned short*)carve((size_t)E * 2);
    unsigned short* w1t = (unsigned short*)carve((size_t)128 * 256 * 2);
    unsigned short* w2t = (unsigned short*)carve((size_t)256 * 256 * 2);
    unsigned short* w3t = (unsigned short*)carve((size_t)256 * 256 * 2);
    unsigned short* xb  = (unsigned short*)carve((size_t)M * 128 * 2);
    unsigned short* ab  = (unsigned short*)carve((size_t)M * 256 * 2);   // a1/a2/a3 (bf16)
    unsigned char* h8   = (unsigned char*)d_out;                         // h1/h2 int8
    float* scales       = (float*)((char*)d_out + (size_t)M * 256);      // 4 per node

    // 1) CSR build (rank trick: no atomics in fill)
    hipMemsetAsync(counts, 0, (size_t)M * 4, stream);
    k_hist<<<(E + 255) / 256, 256, 0, stream>>>(dstp, counts, rank, E);
    k_psum<<<nscan, 256, 0, stream>>>(counts, part, M);
    k_scatter_rs<<<nscan, 256, 0, stream>>>(counts, part, row_start, M, E);
    k_fill<<<(E + 255) / 256, 256, 0, stream>>>(srcp, dstp, rank, row_start, csrc, E);

    // 2) conversions (single launch)
    int n4x = M * 128 / 4;
    int nbx = (n4x + 255) / 256;
    k_cvt_all<<<nbx + 128 + 256 + 256, 256, 0, stream>>>(
        (const float4*)x, (ushort4*)xb, n4x, nbx, W1, w1t, W2, w2t, W3, w3t);

    dim3 ggrid(4, (M + 255) / 256);
    int aggblocks = (M * 64 + 255) / 256;

    // layer 1: a1 = agg(x); h1 = quant8(relu(a1 @ W1 + b1))
    k_agg<<<aggblocks, 256, 0, stream>>>(xb, row_start, csrc, ab, M);
    k_gemm<true, 128><<<ggrid, 256, 0, stream>>>(ab, w1t, b1, h8, scales, M);

    // layer 2: a2 = agg8(h1); h2 = quant8(relu(a2 @ W2 + b2))
    k_agg8<<<aggblocks, 256, 0, stream>>>(h8, scales, row_start, csrc, ab, M);
    k_gemm<true, 256><<<ggrid, 256, 0, stream>>>(ab, w2t, b2, h8, scales, M);

    // layer 3: a3 = agg8(h2); out = relu(a3 @ W3 + b3)
    k_agg8<<<aggblocks, 256, 0, stream>>>(h8, scales, row_start, csrc, ab, M);
    k_gemm<false, 256><<<ggrid, 256, 0, stream>>>(ab, w3t, b3, d_out, nullptr, M);
}

// Round 19
// 333.897 us; speedup vs baseline: 1.1249x; 1.0113x over previous
//
#include <hip/hip_runtime.h>
#include <hip/hip_bf16.h>

// ---------------- helpers ----------------
typedef __attribute__((ext_vector_type(8))) short bf16x8;
typedef __attribute__((ext_vector_type(4))) float f32x4;
typedef __attribute__((ext_vector_type(2))) float f32x2;

__device__ __forceinline__ unsigned short f2bf(float f) {
    __hip_bfloat16 h = __float2bfloat16(f);   // round-to-nearest-even
    return __builtin_bit_cast(unsigned short, h);
}
// unpack packed bf16 pair -> f32x2 {lo, hi}
__device__ __forceinline__ f32x2 up2(unsigned int u) {
    f32x2 r;
    r.x = __builtin_bit_cast(float, u << 16);
    r.y = __builtin_bit_cast(float, u & 0xffff0000u);
    return r;
}
__device__ __forceinline__ unsigned int packbf(float lo, float hi) {
    return (unsigned int)f2bf(lo) | ((unsigned int)f2bf(hi) << 16);
}

// ---------------- CSR build ----------------
__global__ void k_hist(const int* __restrict__ dst, int* __restrict__ counts,
                       int* __restrict__ rank, int E) {
    int e = blockIdx.x * blockDim.x + threadIdx.x;
    if (e < E) rank[e] = atomicAdd(&counts[dst[e]], 1);
}

__global__ void k_psum(const int* __restrict__ counts, int* __restrict__ part, int NN) {
    __shared__ int s[256];
    int t = threadIdx.x;
    int i = blockIdx.x * 256 + t;
    s[t] = (i < NN) ? counts[i] : 0;
    __syncthreads();
    for (int off = 128; off > 0; off >>= 1) {
        if (t < off) s[t] += s[t + off];
        __syncthreads();
    }
    if (t == 0) part[blockIdx.x] = s[0];
}

__global__ void k_scatter_rs(const int* __restrict__ counts, const int* __restrict__ part,
                             int* __restrict__ row_start, int NN, int E) {
    __shared__ int s[256];
    __shared__ int q[256];
    int t = threadIdx.x;
    int b = blockIdx.x;
    q[t] = (t < b) ? part[t] : 0;
    __syncthreads();
    for (int off = 128; off > 0; off >>= 1) {
        if (t < off) q[t] += q[t + off];
        __syncthreads();
    }
    int boff = q[0];
    __syncthreads();
    int i = b * 256 + t;
    int v = (i < NN) ? counts[i] : 0;
    s[t] = v; __syncthreads();
    for (int off = 1; off < 256; off <<= 1) {
        int u = (t >= off) ? s[t - off] : 0;
        __syncthreads();
        s[t] += u;
        __syncthreads();
    }
    int ex = s[t] - v + boff;
    if (i < NN) row_start[i] = ex;
    if (i == NN - 1) row_start[NN] = E;
}

__global__ void k_fill(const int* __restrict__ src, const int* __restrict__ dst,
                       const int* __restrict__ rank, const int* __restrict__ row_start,
                       unsigned short* __restrict__ csrc, int E) {
    int e = blockIdx.x * blockDim.x + threadIdx.x;
    if (e < E) csrc[row_start[dst[e]] + rank[e]] = (unsigned short)src[e];
}

// ---------------- fused dtype conversions (one launch) ----------------
// x is quantized to SIGNED int8 with a per-node fp32 scale (one wave per
// node: 2 f32/lane, 6-shfl absmax, packed ushort store -> 128-B rows).
// Halves layer-1 gather lines (2 vs 4 per row). Numerics harness-proven
// (rounds 9/13 passed, absmax 8.0).
__global__ void k_cvt_all(const float* __restrict__ x, unsigned char* __restrict__ xq,
                          float* __restrict__ xsc, int M, int nbq,
                          const float* __restrict__ W1, unsigned short* __restrict__ w1t,
                          const float* __restrict__ W2, unsigned short* __restrict__ w2t,
                          const float* __restrict__ W3, unsigned short* __restrict__ w3t) {
    int b = blockIdx.x;
    int tid = threadIdx.x;
    if (b < nbq) {
        int node = b * 4 + (tid >> 6);
        if (node < M) {
            int lane = tid & 63;
            float2 v = ((const float2*)x)[(size_t)node * 64 + lane];
            float m = fmaxf(fabsf(v.x), fabsf(v.y));
#pragma unroll
            for (int off = 1; off <= 32; off <<= 1)
                m = fmaxf(m, __shfl_xor(m, off, 64));
            float inv = m > 0.f ? 127.0f / m : 0.f;
            int qx = (int)rintf(v.x * inv);
            int qy = (int)rintf(v.y * inv);
            unsigned pk = (unsigned)(qx & 0xff) | ((unsigned)(qy & 0xff) << 8);
            ((unsigned short*)xq)[(size_t)node * 64 + lane] = (unsigned short)pk;
            if (lane == 0) xsc[node] = m * (1.0f / 127.0f);
        }
        return;
    }
    b -= nbq;
    const float* w; unsigned short* wt; int K;
    if (b < 128)      { w = W1; wt = w1t; K = 128; }
    else if (b < 384) { w = W2; wt = w2t; K = 256; b -= 128; }
    else              { w = W3; wt = w3t; K = 256; b -= 384; }
    int i = b * 256 + tid;           // i < K*256
    int k = i >> 8, n = i & 255;
    wt[n * K + k] = f2bf(w[i]);
}

// ---------------- int8 x CSR aggregation (layer 1, 128-B rows) ----------------
// Round-6 champion inner loop (full-wave-per-edge, ping-pong-2) grafted
// onto int8 x: lane owns feats {2l, 2l+1} (2 bytes of the 128-B row).
// Per edge: 1 shfl + 1 ushort load + 1 broadcast scale + ~6 VALU; masked
// slots contribute 0 via zeroed scale (gather address always legal).
__global__ __launch_bounds__(256)
void k_aggx(const unsigned char* __restrict__ xq, const float* __restrict__ xsc,
            const int* __restrict__ rs, const unsigned short* __restrict__ csrc,
            unsigned short* __restrict__ out, int NN) {
    int gid = blockIdx.x * blockDim.x + threadIdx.x;
    int node = gid >> 6;
    if (node >= NN) return;
    int lane = threadIdx.x & 63;
    int k0 = rs[node], k1 = rs[node + 1];
    int cnt = k1 - k0;
    const unsigned char* hl = xq + lane * 2;

    f32x2 acc = {0.f, 0.f};

    for (int base = 0; base < cnt; base += 64) {
        int nk = min(cnt - base, 64);
        int myidx = (lane < nk) ? (int)csrc[k0 + base + lane] : 0;
        int nb = (nk + 3) >> 2;

        auto issue = [&](int j, unsigned (&v)[4], float (&s)[4]) {
#pragma unroll
            for (int b = 0; b < 4; ++b) {
                int row = __shfl(myidx, j + b, 64);
                v[b] = *(const unsigned short*)(hl + ((size_t)row << 7));
                s[b] = xsc[row];
            }
        };
        auto consume = [&](int j, unsigned (&v)[4], float (&s)[4]) {
#pragma unroll
            for (int b = 0; b < 4; ++b) {
                float sc = (j + b < nk) ? s[b] : 0.f;
                f32x2 s2 = {sc, sc};
                unsigned x = v[b];
                int b0 = (int)(signed char)(x & 0xff);
                int b1 = (int)(signed char)((x >> 8) & 0xff);
                acc += (f32x2){(float)b0, (float)b1} * s2;
            }
        };

        unsigned vA[4], vB[4]; float sA[4], sB[4];
        issue(0, vA, sA);
        for (int b = 1; b < nb; ++b) {
            if (b & 1) { issue(b * 4, vB, sB); consume((b - 1) * 4, vA, sA); }
            else       { issue(b * 4, vA, sA); consume((b - 1) * 4, vB, sB); }
        }
        if (nb & 1) consume((nb - 1) * 4, vA, sA);
        else        consume((nb - 1) * 4, vB, sB);
    }

    // lane owns feats {2*lane, 2*lane+1} -> coalesced 4-B store per lane
    *(unsigned*)((unsigned char*)out + (size_t)node * 256 + lane * 4) = packbf(acc.x, acc.y);
}

// ---------------- int8 CSR aggregation (layers 2&3) ----------------
// MEASURED CHAMPION inner loop (round 6, agg8 42.3 us). Full-wave-per-
// edge: lane l owns bytes [4l,4l+4) of the 256-B row, quarter q = lane>>4
// selects the per-(row,64-col) scale. Ping-pong-2 keeps 8 edges in
// flight; masked slots contribute 0 via zeroed scale.
__global__ __launch_bounds__(256)
void k_agg8(const unsigned char* __restrict__ h8, const float* __restrict__ scales,
            const int* __restrict__ rs, const unsigned short* __restrict__ csrc,
            unsigned short* __restrict__ out, int NN) {
    int gid = blockIdx.x * blockDim.x + threadIdx.x;
    int node = gid >> 6;
    if (node >= NN) return;
    int lane = threadIdx.x & 63;
    int q = lane >> 4;                 // 64-col quarter of this lane's 4 feats
    int k0 = rs[node], k1 = rs[node + 1];
    int cnt = k1 - k0;

    f32x2 a0 = {0.f, 0.f}, a1 = {0.f, 0.f};

    for (int base = 0; base < cnt; base += 64) {
        int nk = min(cnt - base, 64);
        int myidx = (lane < nk) ? (int)csrc[k0 + base + lane] : 0;
        int nb = (nk + 3) >> 2;

        auto issue = [&](int j, unsigned (&v)[4], float (&s)[4]) {
#pragma unroll
            for (int b = 0; b < 4; ++b) {
                int row = __shfl(myidx, j + b, 64);
                v[b] = *(const unsigned*)(h8 + (size_t)row * 256 + lane * 4);
                s[b] = scales[row * 4 + q];
            }
        };
        auto consume = [&](int j, unsigned (&v)[4], float (&s)[4]) {
#pragma unroll
            for (int b = 0; b < 4; ++b) {
                float sc = (j + b < nk) ? s[b] : 0.f;
                f32x2 s2 = {sc, sc};
                unsigned x = v[b];
                a0 += (f32x2){(float)(x & 0xff), (float)((x >> 8) & 0xff)} * s2;
                a1 += (f32x2){(float)((x >> 16) & 0xff), (float)(x >> 24)} * s2;
            }
        };

        unsigned vA[4], vB[4]; float sA[4], sB[4];
        issue(0, vA, sA);
        for (int b = 1; b < nb; ++b) {
            if (b & 1) { issue(b * 4, vB, sB); consume((b - 1) * 4, vA, sA); }
            else       { issue(b * 4, vA, sA); consume((b - 1) * 4, vB, sB); }
        }
        if (nb & 1) consume((nb - 1) * 4, vA, sA);
        else        consume((nb - 1) * 4, vB, sB);
    }

    // lane owns feats [4*lane, 4*lane+4) -> coalesced 8-B store per lane
    uint2 o; o.x = packbf(a0.x, a0.y); o.y = packbf(a1.x, a1.y);
    *(uint2*)((unsigned char*)out + (size_t)node * 512 + lane * 8) = o;
}

// ---------------- MFMA GEMM: C = relu(A @ W + b) ----------------
// Stage-B-once design (round 2/4). K <= 256 so a block's 64-col B-slab
// (16-32 KB) is staged in LDS ONCE, one __syncthreads, then a fully-
// unrolled barrier-free K-loop with A direct from global (line-perfect:
// 16 rows x 64 B per fragment load) and B from LDS (padded stride K+8).
// QUANT epilogue: row-major h8 + per-(row, 64-col) fp32 scale.
template <bool QUANT, int K>
__global__ __launch_bounds__(256, 4)
void k_gemm(const unsigned short* __restrict__ A, const unsigned short* __restrict__ Bt,
            const float* __restrict__ bias, void* __restrict__ Cout,
            float* __restrict__ scales, int M) {
    constexpr int LDB = K + 8;
    __shared__ unsigned short Bs[64 * LDB];
    int tid = threadIdx.x;
    int lane = tid & 63, quad = lane >> 4, l16 = lane & 15;
    int w = tid >> 6;
    int cbase = blockIdx.x * 64;
    int mrow0 = blockIdx.y * 256 + w * 64;

    // stage the block's B slab (64 cols x K) once
    constexpr int CH = K / 8;            // uint4 chunks per slab row
    constexpr int NCH = 64 * CH;
#pragma unroll
    for (int ch = tid; ch < NCH; ch += 256) {
        int c = ch / CH;
        int kk = (ch % CH) * 8;
        uint4 v = *((const uint4*)(Bt + (size_t)(cbase + c) * K + kk));
        *((uint4*)&Bs[c * LDB + kk]) = v;
    }
    __syncthreads();

    // A fragment base pointers (rows clamped; tail rows never stored)
    const unsigned short* Ap[4];
#pragma unroll
    for (int mt = 0; mt < 4; ++mt) {
        int r = mrow0 + mt * 16 + l16;
        if (r >= M) r = M - 1;
        Ap[mt] = A + (size_t)r * K + quad * 8;
    }

    f32x4 acc[4][4];
#pragma unroll
    for (int i = 0; i < 4; ++i)
#pragma unroll
        for (int j = 0; j < 4; ++j) acc[i][j] = (f32x4){0.f, 0.f, 0.f, 0.f};

#pragma unroll
    for (int s = 0; s < K / 32; ++s) {
        bf16x8 af[4], bfr[4];
#pragma unroll
        for (int mt = 0; mt < 4; ++mt) af[mt] = *((const bf16x8*)(Ap[mt] + s * 32));
#pragma unroll
        for (int nt = 0; nt < 4; ++nt)
            bfr[nt] = *((const bf16x8*)&Bs[(nt * 16 + l16) * LDB + s * 32 + quad * 8]);
#pragma unroll
        for (int mt = 0; mt < 4; ++mt)
#pragma unroll
            for (int nt = 0; nt < 4; ++nt)
                acc[mt][nt] = __builtin_amdgcn_mfma_f32_16x16x32_bf16(af[mt], bfr[nt], acc[mt][nt], 0, 0, 0);
    }

    // bias + relu in-place.  C/D layout: col = lane&15, row = quad*4 + reg
    float bv[4];
#pragma unroll
    for (int nt = 0; nt < 4; ++nt) bv[nt] = bias[cbase + nt * 16 + l16];
#pragma unroll
    for (int mt = 0; mt < 4; ++mt)
#pragma unroll
        for (int nt = 0; nt < 4; ++nt)
#pragma unroll
            for (int r = 0; r < 4; ++r) {
                float v = acc[mt][nt][r] + bv[nt];
                acc[mt][nt][r] = v > 0.f ? v : 0.f;
            }

    if constexpr (QUANT) {
        unsigned char* h8 = (unsigned char*)Cout;
        int qid = blockIdx.x;            // 64-col quarter id
#pragma unroll
        for (int mt = 0; mt < 4; ++mt) {
#pragma unroll
            for (int r = 0; r < 4; ++r) {
                float mx = fmaxf(fmaxf(acc[mt][0][r], acc[mt][1][r]),
                                 fmaxf(acc[mt][2][r], acc[mt][3][r]));
#pragma unroll
                for (int off = 1; off < 16; off <<= 1)
                    mx = fmaxf(mx, __shfl_xor(mx, off, 64));
                float inv = mx > 0.f ? 255.0f / mx : 0.0f;
                int m = mrow0 + mt * 16 + quad * 4 + r;
                if (m < M) {
#pragma unroll
                    for (int nt = 0; nt < 4; ++nt) {
                        int n = cbase + nt * 16 + l16;
                        unsigned u = (unsigned)(acc[mt][nt][r] * inv + 0.5f);
                        h8[(size_t)m * 256 + n] = (unsigned char)u;
                    }
                    if (l16 == 0) scales[(size_t)m * 4 + qid] = mx * (1.0f / 255.0f);
                }
            }
        }
    } else {
        float* C = (float*)Cout;
#pragma unroll
        for (int mt = 0; mt < 4; ++mt)
#pragma unroll
            for (int nt = 0; nt < 4; ++nt) {
                int n = cbase + nt * 16 + l16;
#pragma unroll
                for (int r = 0; r < 4; ++r) {
                    int m = mrow0 + mt * 16 + quad * 4 + r;
                    if (m < M) C[(size_t)m * 256 + n] = acc[mt][nt][r];
                }
            }
    }
}

// ---------------- host ----------------
static inline size_t alignup(size_t x) { return (x + 255) & ~(size_t)255; }

extern "C" void kernel_launch(void* const* d_in, const int* in_sizes, int n_in,
                              void* d_out, int out_size, void* d_ws, size_t ws_size,
                              hipStream_t stream) {
    const float* x  = (const float*)d_in[0];
    const int* ei   = (const int*)d_in[1];    // int32 on device (harness converts)
    const float* W1 = (const float*)d_in[2];
    const float* b1 = (const float*)d_in[3];
    const float* W2 = (const float*)d_in[4];
    const float* b2 = (const float*)d_in[5];
    const float* W3 = (const float*)d_in[6];
    const float* b3 = (const float*)d_in[7];

    const int M = in_sizes[0] / 128;      // 50000 nodes
    const int E = in_sizes[1] / 2;        // 800000 edges
    const int* srcp = ei;
    const int* dstp = ei + E;
    const int nscan = (M + 255) / 256;

    // workspace carve-up. h8 (12.8 MB) + scales (0.8 MB) live in d_out:
    // both dead before gemm3 overwrites d_out with fp32.
    char* p = (char*)d_ws;
    size_t off = 0;
    auto carve = [&](size_t bytes) { void* r = p + off; off += alignup(bytes); return r; };
    int* counts    = (int*)carve((size_t)M * 4);
    int* row_start = (int*)carve((size_t)(M + 1) * 4);
    int* part      = (int*)carve((size_t)256 * 4);
    int* rank      = (int*)carve((size_t)E * 4);
    unsigned short* csrc = (unsigned short*)carve((size_t)E * 2);
    unsigned short* w1t = (unsigned short*)carve((size_t)128 * 256 * 2);
    unsigned short* w2t = (unsigned short*)carve((size_t)256 * 256 * 2);
    unsigned short* w3t = (unsigned short*)carve((size_t)256 * 256 * 2);
    unsigned char* xq   = (unsigned char*)carve((size_t)M * 128);        // int8 x
    float* xsc          = (float*)carve((size_t)M * 4);                  // per-node x scale
    unsigned short* ab  = (unsigned short*)carve((size_t)M * 256 * 2);   // a1/a2/a3 (bf16)
    unsigned char* h8   = (unsigned char*)d_out;                         // h1/h2 int8
    float* scales       = (float*)((char*)d_out + (size_t)M * 256);      // 4 per node

    // 1) CSR build (rank trick: no atomics in fill)
    hipMemsetAsync(counts, 0, (size_t)M * 4, stream);
    k_hist<<<(E + 255) / 256, 256, 0, stream>>>(dstp, counts, rank, E);
    k_psum<<<nscan, 256, 0, stream>>>(counts, part, M);
    k_scatter_rs<<<nscan, 256, 0, stream>>>(counts, part, row_start, M, E);
    k_fill<<<(E + 255) / 256, 256, 0, stream>>>(srcp, dstp, rank, row_start, csrc, E);

    // 2) conversions (single launch): x -> int8 + per-node scale, W -> bf16^T
    int nbq = (M + 3) / 4;
    k_cvt_all<<<nbq + 128 + 256 + 256, 256, 0, stream>>>(
        x, xq, xsc, M, nbq, W1, w1t, W2, w2t, W3, w3t);

    dim3 ggrid(4, (M + 255) / 256);
    int aggblocks = (M * 64 + 255) / 256;

    // layer 1: a1 = agg(xq*xsc); h1 = quant8(relu(a1 @ W1 + b1))
    k_aggx<<<aggblocks, 256, 0, stream>>>(xq, xsc, row_start, csrc, ab, M);
    k_gemm<true, 128><<<ggrid, 256, 0, stream>>>(ab, w1t, b1, h8, scales, M);

    // layer 2: a2 = agg8(h1); h2 = quant8(relu(a2 @ W2 + b2))
    k_agg8<<<aggblocks, 256, 0, stream>>>(h8, scales, row_start, csrc, ab, M);
    k_gemm<true, 256><<<ggrid, 256, 0, stream>>>(ab, w2t, b2, h8, scales, M);

    // layer 3: a3 = agg8(h2); out = relu(a3 @ W3 + b3)
    k_agg8<<<aggblocks, 256, 0, stream>>>(h8, scales, row_start, csrc, ab, M);
    k_gemm<false, 256><<<ggrid, 256, 0, stream>>>(ab, w3t, b3, d_out, nullptr, M);
}